// Round 1
// baseline (1653.583 us; speedup 1.0000x reference)
//
#include <hip/hip_runtime.h>
#include <cstdint>
#include <cstddef>

#define T_TOK 2048
#define H_DIM 2048
#define I_DIM 1024
#define E_NUM 32
#define K_TOP 6
#define G_NUM 8
#define TG_SEL 4
#define ROUTE_SCALE 2.5f
#define LDSP 40   // LDS row pitch in bf16 elems (40*2=80B -> 20 banks, breaks conflicts)

#define LOGIT_OFF ((size_t)T_TOK * H_DIM)
#define IDX_OFF   (LOGIT_OFF + (size_t)T_TOK * E_NUM)

typedef __attribute__((ext_vector_type(8))) short bf16x8;
typedef __attribute__((ext_vector_type(4))) float f32x4;

__device__ __forceinline__ short f2bf(float f) {
  unsigned u = __float_as_uint(f);
  u += 0x7fffu + ((u >> 16) & 1u);   // RNE
  return (short)(u >> 16);
}

// ---------------- gate + routing ----------------
__global__ __launch_bounds__(256)
void gate_kernel(const float* __restrict__ x, const float* __restrict__ gw,
                 const float* __restrict__ bias, float* __restrict__ out,
                 int* __restrict__ counts, int* __restrict__ lists,
                 float* __restrict__ wpair)
{
  const int t = blockIdx.x;
  const int tid = threadIdx.x;
  __shared__ float s_logits[E_NUM];

  const float* xr = x + (size_t)t * H_DIM;
  const int e = tid >> 3;
  const int l8 = tid & 7;
  const float* gr = gw + (size_t)e * H_DIM;
  float acc = 0.f;
  for (int h = l8 * 4; h < H_DIM; h += 32) {
    const float4 xv = *reinterpret_cast<const float4*>(xr + h);
    const float4 gv = *reinterpret_cast<const float4*>(gr + h);
    acc += xv.x * gv.x + xv.y * gv.y + xv.z * gv.z + xv.w * gv.w;
  }
  for (int off = 4; off > 0; off >>= 1) acc += __shfl_down(acc, off, 8);
  if (l8 == 0) {
    s_logits[e] = acc;
    out[LOGIT_OFF + (size_t)t * E_NUM + e] = acc;
  }
  __syncthreads();

  if (tid == 0) {
    float sc[E_NUM], scr[E_NUM];
    for (int i = 0; i < E_NUM; ++i) {
      const float s = 1.f / (1.f + expf(-s_logits[i]));
      sc[i] = s;
      scr[i] = s + bias[i];
    }
    // group scores = sum of top-2 within each group of 4
    float gs[G_NUM];
    for (int g = 0; g < G_NUM; ++g) {
      float m1 = -1e30f, m2 = -1e30f;
      for (int j = 0; j < E_NUM / G_NUM; ++j) {
        const float v = scr[g * (E_NUM / G_NUM) + j];
        if (v > m1) { m2 = m1; m1 = v; } else if (v > m2) { m2 = v; }
      }
      gs[g] = m1 + m2;
    }
    // top TG groups (strict >, first index wins on tie — matches lax.top_k)
    bool gsel[G_NUM];
    for (int g = 0; g < G_NUM; ++g) gsel[g] = false;
    for (int r = 0; r < TG_SEL; ++r) {
      int best = -1; float bv = -1e30f;
      for (int g = 0; g < G_NUM; ++g)
        if (!gsel[g] && gs[g] > bv) { bv = gs[g]; best = g; }
      gsel[best] = true;
    }
    // masked top-K experts
    bool esel[E_NUM];
    for (int i = 0; i < E_NUM; ++i) esel[i] = false;
    int idx[K_TOP]; float tw[K_TOP]; float sum = 0.f;
    for (int r = 0; r < K_TOP; ++r) {
      int best = -1; float bv = -1e30f;
      for (int i = 0; i < E_NUM; ++i)
        if (gsel[i >> 2] && !esel[i] && scr[i] > bv) { bv = scr[i]; best = i; }
      esel[best] = true;
      idx[r] = best;
      tw[r] = sc[best];
      sum += sc[best];
    }
    const float inv = ROUTE_SCALE / (sum + 1e-20f);
    for (int r = 0; r < K_TOP; ++r) {
      out[IDX_OFF + (size_t)t * K_TOP + r] = (float)idx[r];
      const int eid = idx[r];
      const int slot = t * K_TOP + r;
      wpair[slot] = tw[r] * inv;
      const int pos = atomicAdd(&counts[eid], 1);
      lists[eid * T_TOK + pos] = slot;
    }
  }
}

// ---------------- GEMM1: z = silu(X@Wg) * (X@Wu), bf16 out ----------------
// DENSE=0: rows gathered via per-expert lists; DENSE=1: rows = tokens (shared expert)
template <int DENSE>
__global__ __launch_bounds__(256)
void gemm1_kernel(const float* __restrict__ x,
                  const float* __restrict__ WgB, const float* __restrict__ WuB,
                  const int* __restrict__ counts, const int* __restrict__ lists,
                  short* __restrict__ zbuf)
{
  const int e = blockIdx.z;
  const int Ne = DENSE ? T_TOK : counts[e];
  const int m0 = blockIdx.y * 64;
  if (m0 >= Ne) return;
  const int n0 = blockIdx.x * 64;
  const int tid = threadIdx.x;

  __shared__ __align__(16) short As[64 * LDSP];
  __shared__ __align__(16) short Bgs[64 * LDSP];
  __shared__ __align__(16) short Bus[64 * LDSP];
  __shared__ int s_slot[64];
  __shared__ int s_tok[64];

  if (tid < 64) {
    const int r = m0 + tid;
    int sl = -1, tk = -1;
    if (r < Ne) {
      if (DENSE) { sl = T_TOK * K_TOP + r; tk = r; }
      else       { sl = lists[e * T_TOK + r]; tk = sl / K_TOP; }
    }
    s_slot[tid] = sl;
    s_tok[tid] = tk;
  }
  __syncthreads();

  const float* Bg = WgB + (size_t)e * H_DIM * I_DIM;
  const float* Bu = WuB + (size_t)e * H_DIM * I_DIM;

  const int arow = tid >> 2, acol = (tid & 3) * 8;   // A: 64 rows x 32 k
  const int brow = tid >> 3, bcol = (tid & 7) * 8;   // B: 32 k x 64 n
  const int wave = tid >> 6, lane = tid & 63;
  const int lm = lane & 15, lq = lane >> 4;

  f32x4 accg[4], accu[4];
  const f32x4 z4 = {0.f, 0.f, 0.f, 0.f};
#pragma unroll
  for (int i = 0; i < 4; ++i) { accg[i] = z4; accu[i] = z4; }

  const int atok = s_tok[arow];
  const float* aptr = (atok >= 0) ? (x + (size_t)atok * H_DIM + acol) : nullptr;

  for (int k0 = 0; k0 < H_DIM; k0 += 32) {
    // stage A (gathered rows, fp32 -> bf16)
    {
      float4 v0 = {0.f,0.f,0.f,0.f}, v1 = {0.f,0.f,0.f,0.f};
      if (aptr) {
        v0 = *reinterpret_cast<const float4*>(aptr + k0);
        v1 = *reinterpret_cast<const float4*>(aptr + k0 + 4);
      }
      bf16x8 av;
      av[0] = f2bf(v0.x); av[1] = f2bf(v0.y); av[2] = f2bf(v0.z); av[3] = f2bf(v0.w);
      av[4] = f2bf(v1.x); av[5] = f2bf(v1.y); av[6] = f2bf(v1.z); av[7] = f2bf(v1.w);
      *reinterpret_cast<bf16x8*>(&As[arow * LDSP + acol]) = av;
    }
    // stage Bg/Bu transposed: LDS Bs[n][k]
    {
      const size_t boff = (size_t)(k0 + brow) * I_DIM + n0 + bcol;
      const float4 g0 = *reinterpret_cast<const float4*>(Bg + boff);
      const float4 g1 = *reinterpret_cast<const float4*>(Bg + boff + 4);
      const float4 u0 = *reinterpret_cast<const float4*>(Bu + boff);
      const float4 u1 = *reinterpret_cast<const float4*>(Bu + boff + 4);
      float gv[8] = {g0.x,g0.y,g0.z,g0.w,g1.x,g1.y,g1.z,g1.w};
      float uv[8] = {u0.x,u0.y,u0.z,u0.w,u1.x,u1.y,u1.z,u1.w};
#pragma unroll
      for (int j = 0; j < 8; ++j) {
        Bgs[(bcol + j) * LDSP + brow] = f2bf(gv[j]);
        Bus[(bcol + j) * LDSP + brow] = f2bf(uv[j]);
      }
    }
    __syncthreads();

    const bf16x8 af = *reinterpret_cast<const bf16x8*>(&As[(wave * 16 + lm) * LDSP + lq * 8]);
#pragma unroll
    for (int nt = 0; nt < 4; ++nt) {
      const bf16x8 bg = *reinterpret_cast<const bf16x8*>(&Bgs[(nt * 16 + lm) * LDSP + lq * 8]);
      const bf16x8 bu = *reinterpret_cast<const bf16x8*>(&Bus[(nt * 16 + lm) * LDSP + lq * 8]);
      accg[nt] = __builtin_amdgcn_mfma_f32_16x16x32_bf16(af, bg, accg[nt], 0, 0, 0);
      accu[nt] = __builtin_amdgcn_mfma_f32_16x16x32_bf16(af, bu, accu[nt], 0, 0, 0);
    }
    __syncthreads();
  }

  // epilogue: z = silu(g)*u -> zbuf[slot][n]
#pragma unroll
  for (int nt = 0; nt < 4; ++nt) {
#pragma unroll
    for (int r = 0; r < 4; ++r) {
      const int lr = wave * 16 + lq * 4 + r;
      const int sl = s_slot[lr];
      if (sl >= 0) {
        const float g = accg[nt][r], u = accu[nt][r];
        const float zz = (g / (1.f + expf(-g))) * u;
        zbuf[(size_t)sl * I_DIM + n0 + nt * 16 + lm] = f2bf(zz);
      }
    }
  }
}

// ---------------- GEMM2: y += w * (z @ Wd) ----------------
template <int DENSE>
__global__ __launch_bounds__(256)
void gemm2_kernel(const short* __restrict__ zbuf,
                  const float* __restrict__ WdB,
                  const int* __restrict__ counts, const int* __restrict__ lists,
                  const float* __restrict__ wpair,
                  float* __restrict__ y)
{
  const int e = blockIdx.z;
  const int Ne = DENSE ? T_TOK : counts[e];
  const int m0 = blockIdx.y * 64;
  if (m0 >= Ne) return;
  const int n0 = blockIdx.x * 64;
  const int tid = threadIdx.x;

  __shared__ __align__(16) short As[64 * LDSP];
  __shared__ __align__(16) short Bs[64 * LDSP];
  __shared__ int s_slot[64];
  __shared__ int s_tok[64];
  __shared__ float s_w[64];

  if (tid < 64) {
    const int r = m0 + tid;
    int sl = -1, tk = -1; float w = 0.f;
    if (r < Ne) {
      if (DENSE) { sl = T_TOK * K_TOP + r; tk = r; w = 1.f; }
      else       { sl = lists[e * T_TOK + r]; tk = sl / K_TOP; w = wpair[sl]; }
    }
    s_slot[tid] = sl; s_tok[tid] = tk; s_w[tid] = w;
  }
  __syncthreads();

  const float* Bd = WdB + (size_t)e * I_DIM * H_DIM;

  const int arow = tid >> 2, acol = (tid & 3) * 8;
  const int brow = tid >> 3, bcol = (tid & 7) * 8;
  const int wave = tid >> 6, lane = tid & 63;
  const int lm = lane & 15, lq = lane >> 4;

  f32x4 acc[4];
  const f32x4 z4 = {0.f, 0.f, 0.f, 0.f};
#pragma unroll
  for (int i = 0; i < 4; ++i) acc[i] = z4;

  const int aslot = s_slot[arow];
  const short* aptr = (aslot >= 0) ? (zbuf + (size_t)aslot * I_DIM + acol) : nullptr;

  for (int k0 = 0; k0 < I_DIM; k0 += 32) {
    // stage A (bf16 rows of z, direct 16B copy)
    {
      uint4 av = {0u, 0u, 0u, 0u};
      if (aptr) av = *reinterpret_cast<const uint4*>(aptr + k0);
      *reinterpret_cast<uint4*>(&As[arow * LDSP + acol]) = av;
    }
    // stage Wd transposed
    {
      const size_t boff = (size_t)(k0 + brow) * H_DIM + n0 + bcol;
      const float4 d0 = *reinterpret_cast<const float4*>(Bd + boff);
      const float4 d1 = *reinterpret_cast<const float4*>(Bd + boff + 4);
      float dv[8] = {d0.x,d0.y,d0.z,d0.w,d1.x,d1.y,d1.z,d1.w};
#pragma unroll
      for (int j = 0; j < 8; ++j)
        Bs[(bcol + j) * LDSP + brow] = f2bf(dv[j]);
    }
    __syncthreads();

    const bf16x8 af = *reinterpret_cast<const bf16x8*>(&As[(wave * 16 + lm) * LDSP + lq * 8]);
#pragma unroll
    for (int nt = 0; nt < 4; ++nt) {
      const bf16x8 bd = *reinterpret_cast<const bf16x8*>(&Bs[(nt * 16 + lm) * LDSP + lq * 8]);
      acc[nt] = __builtin_amdgcn_mfma_f32_16x16x32_bf16(af, bd, acc[nt], 0, 0, 0);
    }
    __syncthreads();
  }

#pragma unroll
  for (int nt = 0; nt < 4; ++nt) {
#pragma unroll
    for (int r = 0; r < 4; ++r) {
      const int lr = wave * 16 + lq * 4 + r;
      const int sl = s_slot[lr];
      if (sl >= 0) {
        const float v = acc[nt][r] * s_w[lr];
        atomicAdd(&y[(size_t)s_tok[lr] * H_DIM + n0 + nt * 16 + lm], v);
      }
    }
  }
}

// ---------------- launch ----------------
extern "C" void kernel_launch(void* const* d_in, const int* in_sizes, int n_in,
                              void* d_out, int out_size, void* d_ws, size_t ws_size,
                              hipStream_t stream) {
  const float* x      = (const float*)d_in[0];
  const float* gate_w = (const float*)d_in[1];
  const float* bias   = (const float*)d_in[2];
  const float* Wg     = (const float*)d_in[3];
  const float* Wu     = (const float*)d_in[4];
  const float* Wd     = (const float*)d_in[5];
  const float* Wgs    = (const float*)d_in[6];
  const float* Wus    = (const float*)d_in[7];
  const float* Wds    = (const float*)d_in[8];
  float* out = (float*)d_out;

  char* ws = (char*)d_ws;
  const size_t zrows = (size_t)T_TOK * K_TOP + T_TOK;       // routed pairs + shared rows
  short* zbuf  = (short*)ws;                                 // zrows * I_DIM bf16
  float* wpair = (float*)(ws + zrows * I_DIM * sizeof(short));
  int* counts  = (int*)((char*)wpair + (size_t)T_TOK * K_TOP * sizeof(float));
  int* lists   = counts + E_NUM;                             // E_NUM * T_TOK ints

  hipMemsetAsync(d_out, 0, (size_t)out_size * sizeof(float), stream);
  hipMemsetAsync(counts, 0, E_NUM * sizeof(int), stream);

  gate_kernel<<<T_TOK, 256, 0, stream>>>(x, gate_w, bias, out, counts, lists, wpair);

  // routed: up-proj + silu*mul
  gemm1_kernel<0><<<dim3(I_DIM / 64, T_TOK / 64, E_NUM), 256, 0, stream>>>(
      x, Wg, Wu, counts, lists, zbuf);
  // shared expert up-proj
  gemm1_kernel<1><<<dim3(I_DIM / 64, T_TOK / 64, 1), 256, 0, stream>>>(
      x, Wgs, Wus, counts, lists, zbuf);
  // routed: down-proj + weighted scatter-add
  gemm2_kernel<0><<<dim3(H_DIM / 64, T_TOK / 64, E_NUM), 256, 0, stream>>>(
      zbuf, Wd, counts, lists, wpair, out);
  // shared expert down-proj
  gemm2_kernel<1><<<dim3(H_DIM / 64, T_TOK / 64, 1), 256, 0, stream>>>(
      zbuf, Wds, counts, lists, wpair, out);
}